// Round 3
// baseline (448.981 us; speedup 1.0000x reference)
//
#include <hip/hip_runtime.h>
#include <math.h>

// MessagePassingUnitGatingWithRelnessLogits fused kernel, MI355X (gfx950).
// N=32768 rows; D=1024 (paired=2048); A=256; FD=64; F8=8.
// Block = 16 rows, 256 threads (4 waves).
// v4: v3 + register retention of bf16(relu(x)) across phases. Phase 2 no
//     longer re-reads x from global: it unpacks the retained short8s,
//     normalizes in-register, and feeds MFMA. Only ln_g/ln_b + wfrag
//     (both L2-hot) are loaded in phase 2. VGPR ~120 (4 waves/SIMD tier).

#define EPS_LN 1e-5f

typedef __attribute__((ext_vector_type(8))) short short8;   // 8 x bf16 (4 VGPRs)
typedef __attribute__((ext_vector_type(4))) float f32x4;    // MFMA accumulator

__device__ __forceinline__ unsigned short f2bf(float f) {
  unsigned int u = __float_as_uint(f);
  u += 0x7FFFu + ((u >> 16) & 1u);      // round-to-nearest-even
  return (unsigned short)(u >> 16);
}

// pack two fp32 -> one u32 of 2 x bf16 (RNE), low half = a
__device__ __forceinline__ unsigned pkbf2(float a, float b) {
  unsigned ua = __float_as_uint(a), ub = __float_as_uint(b);
  ua += 0x7FFFu + ((ua >> 16) & 1u);
  ub += 0x7FFFu + ((ub >> 16) & 1u);
  return (ub & 0xFFFF0000u) | (ua >> 16);
}

union S8U { unsigned u[4]; short8 v; };

__device__ __forceinline__ short8 pack8(float x0, float x1, float x2, float x3,
                                        float x4, float x5, float x6, float x7) {
  S8U r;
  r.u[0] = pkbf2(x0, x1); r.u[1] = pkbf2(x2, x3);
  r.u[2] = pkbf2(x4, x5); r.u[3] = pkbf2(x6, x7);
  return r.v;
}

__device__ __forceinline__ short8 ones8() {
  S8U r; r.u[0] = r.u[1] = r.u[2] = r.u[3] = 0x3F803F80u;  // bf16 1.0 pairs
  return r.v;
}

__device__ __forceinline__ float sigmoidf_(float x) {
  return 1.0f / (1.0f + __expf(-x));
}

// reverse_sigmoid forward: clip to [0.001,0.999], then logit
__device__ __forceinline__ float rsigf(float x) {
  float y = fminf(fmaxf(x, 0.001f), 0.999f);
  return logf(y) - log1pf(-y);
}

// ---------------------------------------------------------------------------
// Prep: W [2048][64] fp32 -> bf16 B-fragments in MFMA operand order, plus
// W_aux [256][8] -> bf16 B-fragments (cols 8..15 zero).
// Main: frag[((ntile*64 + kb)*64 + lane)*8 + j] = bf16(W[k][f]),
//   f = ntile*16 + (lane&15), k = kb*32 + (lane>>4)*8 + j.
// Aux (blocks 256..263): auxfrag[((kb*64)+lane)*8 + j] = bf16(W_aux[k][f]) or 0.
// grid = 264 blocks x 64 threads.
// ---------------------------------------------------------------------------
__global__ void prep_frags(const float* __restrict__ W,
                           const float* __restrict__ W_aux,
                           unsigned short* __restrict__ wfrag) {
  const int lane = threadIdx.x;
  const int b = blockIdx.x;
  unsigned short tmp[8];
  if (b < 256) {
    const int ntile = b >> 6;
    const int kb = b & 63;
    const int f = (ntile << 4) + (lane & 15);
    const int kbase = (kb << 5) + ((lane >> 4) << 3);
#pragma unroll
    for (int j = 0; j < 8; ++j) tmp[j] = f2bf(W[(size_t)(kbase + j) * 64 + f]);
    ushort4* dst = reinterpret_cast<ushort4*>(wfrag + (((size_t)b * 64 + lane) << 3));
    dst[0] = make_ushort4(tmp[0], tmp[1], tmp[2], tmp[3]);
    dst[1] = make_ushort4(tmp[4], tmp[5], tmp[6], tmp[7]);
  } else {
    const int kb = b - 256;             // 0..7
    const int f = lane & 15;
    const int kbase = (kb << 5) + ((lane >> 4) << 3);
#pragma unroll
    for (int j = 0; j < 8; ++j)
      tmp[j] = (f < 8) ? f2bf(W_aux[(size_t)(kbase + j) * 8 + f]) : (unsigned short)0;
    ushort4* dst = reinterpret_cast<ushort4*>(wfrag + 131072 +
                                              (((size_t)kb * 64 + lane) << 3));
    dst[0] = make_ushort4(tmp[0], tmp[1], tmp[2], tmp[3]);
    dst[1] = make_ushort4(tmp[4], tmp[5], tmp[6], tmp[7]);
  }
}

// ---------------------------------------------------------------------------
// Main fused kernel.
// ---------------------------------------------------------------------------
__global__ void __launch_bounds__(256, 4) fused_main(
    const float* __restrict__ unary, const float* __restrict__ pair,
    const float* __restrict__ aux, const float* __restrict__ auxw,
    const float* __restrict__ ln_g, const float* __restrict__ ln_b,
    const float* __restrict__ b_lin,
    const float* __restrict__ ln_ag, const float* __restrict__ ln_ab,
    const float* __restrict__ b_aux,
    const float* __restrict__ gw, const float* __restrict__ agw,
    const unsigned short* __restrict__ wfrag,
    float* __restrict__ out, float* __restrict__ out_g) {
  // Cross-wave f32 partial tiles [wave][row][f], f-stride 68 to avoid aliasing.
  __shared__ float part[4][16][68];     // 17408 B
  __shared__ float auxpart[4][16][8];   // 2048 B
  __shared__ float4 statp[4][16];       // per-wave (S, Q, Sa, Qa) per row, 1 KB

  const int tid = threadIdx.x;
  const int w = tid >> 6;     // wave 0..3
  const int lane = tid & 63;
  const int base = blockIdx.x << 4;
  const int m = lane & 15;    // A row (block row) in fragment layout
  const int q = lane >> 4;    // k sub-chunk within 32-k tile

  // Wave k-quarter: w0,w1 -> unary halves 0,1; w2,w3 -> pair halves 0,1.
  const float* srcp = (w < 2) ? unary : pair;
  const float* arow = srcp + (size_t)(base + m) * 1024 + ((w & 1) << 9) + (q << 3);
  const float* axrow = aux + (size_t)(base + m) * 256 + (w << 6) + (q << 3);

  const short8 onef = ones8();

  // ------------- phase 1: stat MFMAs (Σx, Σx² for main; Σa, Σa² for aux) ----
  f32x4 aS = {0.f,0.f,0.f,0.f}, aQ = {0.f,0.f,0.f,0.f};
  f32x4 sS = {0.f,0.f,0.f,0.f}, sQ = {0.f,0.f,0.f,0.f};
  float axv[16];              // retained raw aux values (this lane's 16 k's)
  short8 ar[16];              // retained bf16(relu(x)) for phase-2 normalize

#pragma unroll
  for (int kb = 0; kb < 2; ++kb) {
    const float4 x0 = *reinterpret_cast<const float4*>(axrow + (kb << 5));
    const float4 x1 = *reinterpret_cast<const float4*>(axrow + (kb << 5) + 4);
    axv[kb * 8 + 0] = x0.x; axv[kb * 8 + 1] = x0.y;
    axv[kb * 8 + 2] = x0.z; axv[kb * 8 + 3] = x0.w;
    axv[kb * 8 + 4] = x1.x; axv[kb * 8 + 5] = x1.y;
    axv[kb * 8 + 6] = x1.z; axv[kb * 8 + 7] = x1.w;
    const short8 a = pack8(x0.x, x0.y, x0.z, x0.w, x1.x, x1.y, x1.z, x1.w);
    const short8 a2 = pack8(x0.x * x0.x, x0.y * x0.y, x0.z * x0.z, x0.w * x0.w,
                            x1.x * x1.x, x1.y * x1.y, x1.z * x1.z, x1.w * x1.w);
    sS = __builtin_amdgcn_mfma_f32_16x16x32_bf16(a, onef, sS, 0, 0, 0);
    sQ = __builtin_amdgcn_mfma_f32_16x16x32_bf16(a2, onef, sQ, 0, 0, 0);
  }

#pragma unroll
  for (int kb = 0; kb < 16; ++kb) {
    const float4 x0 = *reinterpret_cast<const float4*>(arow + (kb << 5));
    const float4 x1 = *reinterpret_cast<const float4*>(arow + (kb << 5) + 4);
    const float r0 = fmaxf(x0.x, 0.f), r1 = fmaxf(x0.y, 0.f);
    const float r2 = fmaxf(x0.z, 0.f), r3 = fmaxf(x0.w, 0.f);
    const float r4 = fmaxf(x1.x, 0.f), r5 = fmaxf(x1.y, 0.f);
    const float r6 = fmaxf(x1.z, 0.f), r7 = fmaxf(x1.w, 0.f);
    ar[kb] = pack8(r0, r1, r2, r3, r4, r5, r6, r7);
    const short8 a2 = pack8(r0 * r0, r1 * r1, r2 * r2, r3 * r3,
                            r4 * r4, r5 * r5, r6 * r6, r7 * r7);
    aS = __builtin_amdgcn_mfma_f32_16x16x32_bf16(ar[kb], onef, aS, 0, 0, 0);
    aQ = __builtin_amdgcn_mfma_f32_16x16x32_bf16(a2, onef, aQ, 0, 0, 0);
  }

  // D layout: col = lane&15 (all cols equal with ones-B), row = q*4 + reg.
  // Column-lane 0 of each quad publishes its 4 rows' partials.
  if ((lane & 15) == 0) {
    statp[w][(q << 2) + 0] = make_float4(aS[0], aQ[0], sS[0], sQ[0]);
    statp[w][(q << 2) + 1] = make_float4(aS[1], aQ[1], sS[1], sQ[1]);
    statp[w][(q << 2) + 2] = make_float4(aS[2], aQ[2], sS[2], sQ[2]);
    statp[w][(q << 2) + 3] = make_float4(aS[3], aQ[3], sS[3], sQ[3]);
  }
  __syncthreads();

  // Per-lane stats for row m (needed for phase-2 normalize).
  const float4 s0 = statp[0][m], s1 = statp[1][m], s2 = statp[2][m], s3 = statp[3][m];
  const float S  = s0.x + s1.x + s2.x + s3.x;
  const float Q  = s0.y + s1.y + s2.y + s3.y;
  const float Sa = s0.z + s1.z + s2.z + s3.z;
  const float Qa = s0.w + s1.w + s2.w + s3.w;
  const float mu = S * (1.f / 2048.f);
  const float rs = rsqrtf(Q * (1.f / 2048.f) - mu * mu + EPS_LN);
  const float nmr = -mu * rs;
  const float amu = Sa * (1.f / 256.f);
  const float ars = rsqrtf(Qa * (1.f / 256.f) - amu * amu + EPS_LN);
  const float anmr = -amu * ars;

  // ------------- phase 2: main GEMM from retained registers ----------------
  const float* gp = ln_g + (w << 9) + (q << 3);
  const float* bp = ln_b + (w << 9) + (q << 3);
  const unsigned short* wfp = wfrag + ((size_t)((w << 4) * 64 + lane) << 3);

  f32x4 acc[4] = {{0.f,0.f,0.f,0.f},{0.f,0.f,0.f,0.f},
                  {0.f,0.f,0.f,0.f},{0.f,0.f,0.f,0.f}};
#pragma unroll
  for (int kb = 0; kb < 16; ++kb) {
    const float4 g0 = *reinterpret_cast<const float4*>(gp + (kb << 5));
    const float4 g1 = *reinterpret_cast<const float4*>(gp + (kb << 5) + 4);
    const float4 b0 = *reinterpret_cast<const float4*>(bp + (kb << 5));
    const float4 b1 = *reinterpret_cast<const float4*>(bp + (kb << 5) + 4);
    S8U u; u.v = ar[kb];
    const float r0 = __uint_as_float(u.u[0] << 16);
    const float r1 = __uint_as_float(u.u[0] & 0xFFFF0000u);
    const float r2 = __uint_as_float(u.u[1] << 16);
    const float r3 = __uint_as_float(u.u[1] & 0xFFFF0000u);
    const float r4 = __uint_as_float(u.u[2] << 16);
    const float r5 = __uint_as_float(u.u[2] & 0xFFFF0000u);
    const float r6 = __uint_as_float(u.u[3] << 16);
    const float r7 = __uint_as_float(u.u[3] & 0xFFFF0000u);
    const float n0 = fmaf(r0, rs, nmr), n1 = fmaf(r1, rs, nmr);
    const float n2 = fmaf(r2, rs, nmr), n3 = fmaf(r3, rs, nmr);
    const float n4 = fmaf(r4, rs, nmr), n5 = fmaf(r5, rs, nmr);
    const float n6 = fmaf(r6, rs, nmr), n7 = fmaf(r7, rs, nmr);
    const short8 af = pack8(
        fmaxf(fmaf(n0, g0.x, b0.x), 0.f), fmaxf(fmaf(n1, g0.y, b0.y), 0.f),
        fmaxf(fmaf(n2, g0.z, b0.z), 0.f), fmaxf(fmaf(n3, g0.w, b0.w), 0.f),
        fmaxf(fmaf(n4, g1.x, b1.x), 0.f), fmaxf(fmaf(n5, g1.y, b1.y), 0.f),
        fmaxf(fmaf(n6, g1.z, b1.z), 0.f), fmaxf(fmaf(n7, g1.w, b1.w), 0.f));
#pragma unroll
    for (int nt = 0; nt < 4; ++nt) {
      const short8 bf = *reinterpret_cast<const short8*>(
          wfp + (size_t)nt * 32768 + (kb << 9));
      acc[nt] = __builtin_amdgcn_mfma_f32_16x16x32_bf16(af, bf, acc[nt], 0, 0, 0);
    }
  }

  // Aux GEMM from retained registers (no reload, no shuffles).
  const float* agp = ln_ag + (w << 6) + (q << 3);
  const float* abp = ln_ab + (w << 6) + (q << 3);
  const unsigned short* afp = wfrag + 131072;
  f32x4 acca = {0.f,0.f,0.f,0.f};
#pragma unroll
  for (int kb = 0; kb < 2; ++kb) {
    const float4 g0 = *reinterpret_cast<const float4*>(agp + (kb << 5));
    const float4 g1 = *reinterpret_cast<const float4*>(agp + (kb << 5) + 4);
    const float4 b0 = *reinterpret_cast<const float4*>(abp + (kb << 5));
    const float4 b1 = *reinterpret_cast<const float4*>(abp + (kb << 5) + 4);
    short8 af;
    af[0] = (short)f2bf(fmaxf(fmaf(fmaf(axv[kb*8+0], ars, anmr), g0.x, b0.x), 0.f));
    af[1] = (short)f2bf(fmaxf(fmaf(fmaf(axv[kb*8+1], ars, anmr), g0.y, b0.y), 0.f));
    af[2] = (short)f2bf(fmaxf(fmaf(fmaf(axv[kb*8+2], ars, anmr), g0.z, b0.z), 0.f));
    af[3] = (short)f2bf(fmaxf(fmaf(fmaf(axv[kb*8+3], ars, anmr), g0.w, b0.w), 0.f));
    af[4] = (short)f2bf(fmaxf(fmaf(fmaf(axv[kb*8+4], ars, anmr), g1.x, b1.x), 0.f));
    af[5] = (short)f2bf(fmaxf(fmaf(fmaf(axv[kb*8+5], ars, anmr), g1.y, b1.y), 0.f));
    af[6] = (short)f2bf(fmaxf(fmaf(fmaf(axv[kb*8+6], ars, anmr), g1.z, b1.z), 0.f));
    af[7] = (short)f2bf(fmaxf(fmaf(fmaf(axv[kb*8+7], ars, anmr), g1.w, b1.w), 0.f));
    const short8 bf = *reinterpret_cast<const short8*>(
        afp + ((size_t)(((w << 1) + kb) * 64 + lane) << 3));
    acca = __builtin_amdgcn_mfma_f32_16x16x32_bf16(af, bf, acca, 0, 0, 0);
  }

  // Partial D tiles to LDS: D[row = q*4+reg][f = nt*16 + m] for this k-quarter.
#pragma unroll
  for (int nt = 0; nt < 4; ++nt)
#pragma unroll
    for (int r = 0; r < 4; ++r)
      part[w][(q << 2) + r][(nt << 4) + m] = acc[nt][r];
  if (m < 8) {
#pragma unroll
    for (int r = 0; r < 4; ++r)
      auxpart[w][(q << 2) + r][m] = acca[r];
  }
  __syncthreads();

  // ------------- epilogue: reduce partials, gates, scale pair --------------
  // Lane handles row rl = w*4 + q, main f-quad f0 = 4m; aux f = m&7.
  const int rl = (w << 2) + q;
  const int f0 = m << 2;
  const float4 p0 = *reinterpret_cast<const float4*>(&part[0][rl][f0]);
  const float4 p1 = *reinterpret_cast<const float4*>(&part[1][rl][f0]);
  const float4 p2 = *reinterpret_cast<const float4*>(&part[2][rl][f0]);
  const float4 p3 = *reinterpret_cast<const float4*>(&part[3][rl][f0]);
  const float4 blv = reinterpret_cast<const float4*>(b_lin)[m];
  float sgs = sigmoidf_(p0.x + p1.x + p2.x + p3.x + blv.x)
            + sigmoidf_(p0.y + p1.y + p2.y + p3.y + blv.y)
            + sigmoidf_(p0.z + p1.z + p2.z + p3.z + blv.z)
            + sigmoidf_(p0.w + p1.w + p2.w + p3.w + blv.w);
  sgs += __shfl_xor(sgs, 1);
  sgs += __shfl_xor(sgs, 2);
  sgs += __shfl_xor(sgs, 4);
  sgs += __shfl_xor(sgs, 8);            // sum over all 64 f
  const float gate = sgs * (1.f / 64.f);

  const int fa = m & 7;
  float av4 = auxpart[0][rl][fa] + auxpart[1][rl][fa] +
              auxpart[2][rl][fa] + auxpart[3][rl][fa];
  float axs = sigmoidf_(av4 + b_aux[fa]);
  axs = (m < 8) ? axs : 0.f;
  axs += __shfl_xor(axs, 1);
  axs += __shfl_xor(axs, 2);
  axs += __shfl_xor(axs, 4);
  axs += __shfl_xor(axs, 8);            // sum of 8 aux sigmoids (all m-lanes)
  const float auxg = axs * 0.125f;

  const float logit = gw[0] * rsigf(gate) + agw[0] * rsigf(auxg);
  const float g = sigmoidf_(logit) * auxw[base + rl];
  if (m == 0) out_g[base + rl] = g;

#pragma unroll
  for (int i = 0; i < 4; ++i) {
    const float gi = __shfl(g, (i << 4));   // lane 16i holds row w*4+i's g
    const int row = base + (w << 2) + i;
    const float4* pp = reinterpret_cast<const float4*>(pair + (size_t)row * 1024);
    float4* oo = reinterpret_cast<float4*>(out + (size_t)row * 1024);
#pragma unroll
    for (int j = 0; j < 4; ++j) {
      float4 pv = pp[lane + (j << 6)];
      pv.x *= gi; pv.y *= gi; pv.z *= gi; pv.w *= gi;
      oo[lane + (j << 6)] = pv;
    }
  }
}

extern "C" void kernel_launch(void* const* d_in, const int* in_sizes, int n_in,
                              void* d_out, int out_size, void* d_ws, size_t ws_size,
                              hipStream_t stream) {
  const float* unary = (const float*)d_in[0];
  const float* pair  = (const float*)d_in[1];
  const float* aux   = (const float*)d_in[2];
  const float* auxw  = (const float*)d_in[3];
  const float* ln_g  = (const float*)d_in[4];
  const float* ln_b  = (const float*)d_in[5];
  const float* W     = (const float*)d_in[6];
  const float* b     = (const float*)d_in[7];
  const float* ln_ag = (const float*)d_in[8];
  const float* ln_ab = (const float*)d_in[9];
  const float* W_aux = (const float*)d_in[10];
  const float* b_aux = (const float*)d_in[11];
  const float* gw    = (const float*)d_in[12];
  const float* agw   = (const float*)d_in[13];

  const int N = in_sizes[3];            // 32768
  unsigned short* wfrag = (unsigned short*)d_ws;   // 256 KB main + 8 KB aux frags
  float* out = (float*)d_out;
  float* out_g = out + (size_t)N * 1024;

  prep_frags<<<264, 64, 0, stream>>>(W, W_aux, wfrag);
  fused_main<<<N / 16, 256, 0, stream>>>(unary, pair, aux, auxw, ln_g, ln_b, b,
                                         ln_ag, ln_ab, b_aux, gw, agw,
                                         wfrag, out, out_g);
}

// Round 4
// 420.098 us; speedup vs baseline: 1.0688x; 1.0688x over previous
//
#include <hip/hip_runtime.h>
#include <math.h>

// MessagePassingUnitGatingWithRelnessLogits fused kernel, MI355X (gfx950).
// N=32768 rows; D=1024 (paired=2048); A=256; FD=64; F8=8.
// Block = 16 rows, 256 threads (4 waves).
// v5: v4's register retention of bf16(relu(x)), made to FIT:
//     - __launch_bounds__(256,3): VGPR cap ~168 so ar[16] (64 VGPR) is NOT
//       spilled (v4 @ cap 128 spilled ~150 MB to scratch: WRITE_SIZE 131->281).
//     - aux retained as packed bf16 frags aar[2] (8 VGPR) instead of 16 fp32.
//     Phase 2 touches no global x: unpack retained bf16, normalize, MFMA.

#define EPS_LN 1e-5f

typedef __attribute__((ext_vector_type(8))) short short8;   // 8 x bf16 (4 VGPRs)
typedef __attribute__((ext_vector_type(4))) float f32x4;    // MFMA accumulator

__device__ __forceinline__ unsigned short f2bf(float f) {
  unsigned int u = __float_as_uint(f);
  u += 0x7FFFu + ((u >> 16) & 1u);      // round-to-nearest-even
  return (unsigned short)(u >> 16);
}

// pack two fp32 -> one u32 of 2 x bf16 (RNE), low half = a
__device__ __forceinline__ unsigned pkbf2(float a, float b) {
  unsigned ua = __float_as_uint(a), ub = __float_as_uint(b);
  ua += 0x7FFFu + ((ua >> 16) & 1u);
  ub += 0x7FFFu + ((ub >> 16) & 1u);
  return (ub & 0xFFFF0000u) | (ua >> 16);
}

union S8U { unsigned u[4]; short8 v; };

__device__ __forceinline__ short8 pack8(float x0, float x1, float x2, float x3,
                                        float x4, float x5, float x6, float x7) {
  S8U r;
  r.u[0] = pkbf2(x0, x1); r.u[1] = pkbf2(x2, x3);
  r.u[2] = pkbf2(x4, x5); r.u[3] = pkbf2(x6, x7);
  return r.v;
}

__device__ __forceinline__ short8 ones8() {
  S8U r; r.u[0] = r.u[1] = r.u[2] = r.u[3] = 0x3F803F80u;  // bf16 1.0 pairs
  return r.v;
}

__device__ __forceinline__ float sigmoidf_(float x) {
  return 1.0f / (1.0f + __expf(-x));
}

// reverse_sigmoid forward: clip to [0.001,0.999], then logit
__device__ __forceinline__ float rsigf(float x) {
  float y = fminf(fmaxf(x, 0.001f), 0.999f);
  return logf(y) - log1pf(-y);
}

// ---------------------------------------------------------------------------
// Prep: W [2048][64] fp32 -> bf16 B-fragments in MFMA operand order, plus
// W_aux [256][8] -> bf16 B-fragments (cols 8..15 zero).
// Main: frag[((ntile*64 + kb)*64 + lane)*8 + j] = bf16(W[k][f]),
//   f = ntile*16 + (lane&15), k = kb*32 + (lane>>4)*8 + j.
// Aux (blocks 256..263): auxfrag[((kb*64)+lane)*8 + j] = bf16(W_aux[k][f]) or 0.
// grid = 264 blocks x 64 threads.
// ---------------------------------------------------------------------------
__global__ void prep_frags(const float* __restrict__ W,
                           const float* __restrict__ W_aux,
                           unsigned short* __restrict__ wfrag) {
  const int lane = threadIdx.x;
  const int b = blockIdx.x;
  unsigned short tmp[8];
  if (b < 256) {
    const int ntile = b >> 6;
    const int kb = b & 63;
    const int f = (ntile << 4) + (lane & 15);
    const int kbase = (kb << 5) + ((lane >> 4) << 3);
#pragma unroll
    for (int j = 0; j < 8; ++j) tmp[j] = f2bf(W[(size_t)(kbase + j) * 64 + f]);
    ushort4* dst = reinterpret_cast<ushort4*>(wfrag + (((size_t)b * 64 + lane) << 3));
    dst[0] = make_ushort4(tmp[0], tmp[1], tmp[2], tmp[3]);
    dst[1] = make_ushort4(tmp[4], tmp[5], tmp[6], tmp[7]);
  } else {
    const int kb = b - 256;             // 0..7
    const int f = lane & 15;
    const int kbase = (kb << 5) + ((lane >> 4) << 3);
#pragma unroll
    for (int j = 0; j < 8; ++j)
      tmp[j] = (f < 8) ? f2bf(W_aux[(size_t)(kbase + j) * 8 + f]) : (unsigned short)0;
    ushort4* dst = reinterpret_cast<ushort4*>(wfrag + 131072 +
                                              (((size_t)kb * 64 + lane) << 3));
    dst[0] = make_ushort4(tmp[0], tmp[1], tmp[2], tmp[3]);
    dst[1] = make_ushort4(tmp[4], tmp[5], tmp[6], tmp[7]);
  }
}

// ---------------------------------------------------------------------------
// Main fused kernel.
// ---------------------------------------------------------------------------
__global__ void __launch_bounds__(256, 3) fused_main(
    const float* __restrict__ unary, const float* __restrict__ pair,
    const float* __restrict__ aux, const float* __restrict__ auxw,
    const float* __restrict__ ln_g, const float* __restrict__ ln_b,
    const float* __restrict__ b_lin,
    const float* __restrict__ ln_ag, const float* __restrict__ ln_ab,
    const float* __restrict__ b_aux,
    const float* __restrict__ gw, const float* __restrict__ agw,
    const unsigned short* __restrict__ wfrag,
    float* __restrict__ out, float* __restrict__ out_g) {
  // Cross-wave f32 partial tiles [wave][row][f], f-stride 68 to avoid aliasing.
  __shared__ float part[4][16][68];     // 17408 B
  __shared__ float auxpart[4][16][8];   // 2048 B
  __shared__ float4 statp[4][16];       // per-wave (S, Q, Sa, Qa) per row, 1 KB

  const int tid = threadIdx.x;
  const int w = tid >> 6;     // wave 0..3
  const int lane = tid & 63;
  const int base = blockIdx.x << 4;
  const int m = lane & 15;    // A row (block row) in fragment layout
  const int q = lane >> 4;    // k sub-chunk within 32-k tile

  // Wave k-quarter: w0,w1 -> unary halves 0,1; w2,w3 -> pair halves 0,1.
  const float* srcp = (w < 2) ? unary : pair;
  const float* arow = srcp + (size_t)(base + m) * 1024 + ((w & 1) << 9) + (q << 3);
  const float* axrow = aux + (size_t)(base + m) * 256 + (w << 6) + (q << 3);

  const short8 onef = ones8();

  // ------------- phase 1: stat MFMAs (Σx, Σx² for main; Σa, Σa² for aux) ----
  f32x4 aS = {0.f,0.f,0.f,0.f}, aQ = {0.f,0.f,0.f,0.f};
  f32x4 sS = {0.f,0.f,0.f,0.f}, sQ = {0.f,0.f,0.f,0.f};
  short8 aar[2];              // retained bf16(aux) (this lane's 16 k's, 8 VGPR)
  short8 ar[16];              // retained bf16(relu(x)) (64 VGPR)

#pragma unroll
  for (int kb = 0; kb < 2; ++kb) {
    const float4 x0 = *reinterpret_cast<const float4*>(axrow + (kb << 5));
    const float4 x1 = *reinterpret_cast<const float4*>(axrow + (kb << 5) + 4);
    aar[kb] = pack8(x0.x, x0.y, x0.z, x0.w, x1.x, x1.y, x1.z, x1.w);
    const short8 a2 = pack8(x0.x * x0.x, x0.y * x0.y, x0.z * x0.z, x0.w * x0.w,
                            x1.x * x1.x, x1.y * x1.y, x1.z * x1.z, x1.w * x1.w);
    sS = __builtin_amdgcn_mfma_f32_16x16x32_bf16(aar[kb], onef, sS, 0, 0, 0);
    sQ = __builtin_amdgcn_mfma_f32_16x16x32_bf16(a2, onef, sQ, 0, 0, 0);
  }

#pragma unroll
  for (int kb = 0; kb < 16; ++kb) {
    const float4 x0 = *reinterpret_cast<const float4*>(arow + (kb << 5));
    const float4 x1 = *reinterpret_cast<const float4*>(arow + (kb << 5) + 4);
    const float r0 = fmaxf(x0.x, 0.f), r1 = fmaxf(x0.y, 0.f);
    const float r2 = fmaxf(x0.z, 0.f), r3 = fmaxf(x0.w, 0.f);
    const float r4 = fmaxf(x1.x, 0.f), r5 = fmaxf(x1.y, 0.f);
    const float r6 = fmaxf(x1.z, 0.f), r7 = fmaxf(x1.w, 0.f);
    ar[kb] = pack8(r0, r1, r2, r3, r4, r5, r6, r7);
    const short8 a2 = pack8(r0 * r0, r1 * r1, r2 * r2, r3 * r3,
                            r4 * r4, r5 * r5, r6 * r6, r7 * r7);
    aS = __builtin_amdgcn_mfma_f32_16x16x32_bf16(ar[kb], onef, aS, 0, 0, 0);
    aQ = __builtin_amdgcn_mfma_f32_16x16x32_bf16(a2, onef, aQ, 0, 0, 0);
  }

  // D layout: col = lane&15 (all cols equal with ones-B), row = q*4 + reg.
  // Column-lane 0 of each quad publishes its 4 rows' partials.
  if ((lane & 15) == 0) {
    statp[w][(q << 2) + 0] = make_float4(aS[0], aQ[0], sS[0], sQ[0]);
    statp[w][(q << 2) + 1] = make_float4(aS[1], aQ[1], sS[1], sQ[1]);
    statp[w][(q << 2) + 2] = make_float4(aS[2], aQ[2], sS[2], sQ[2]);
    statp[w][(q << 2) + 3] = make_float4(aS[3], aQ[3], sS[3], sQ[3]);
  }
  __syncthreads();

  // Per-lane stats for row m (needed for phase-2 normalize).
  const float4 s0 = statp[0][m], s1 = statp[1][m], s2 = statp[2][m], s3 = statp[3][m];
  const float S  = s0.x + s1.x + s2.x + s3.x;
  const float Q  = s0.y + s1.y + s2.y + s3.y;
  const float Sa = s0.z + s1.z + s2.z + s3.z;
  const float Qa = s0.w + s1.w + s2.w + s3.w;
  const float mu = S * (1.f / 2048.f);
  const float rs = rsqrtf(Q * (1.f / 2048.f) - mu * mu + EPS_LN);
  const float nmr = -mu * rs;
  const float amu = Sa * (1.f / 256.f);
  const float ars = rsqrtf(Qa * (1.f / 256.f) - amu * amu + EPS_LN);
  const float anmr = -amu * ars;

  // ------------- phase 2: main GEMM from retained registers ----------------
  const float* gp = ln_g + (w << 9) + (q << 3);
  const float* bp = ln_b + (w << 9) + (q << 3);
  const unsigned short* wfp = wfrag + ((size_t)((w << 4) * 64 + lane) << 3);

  f32x4 acc[4] = {{0.f,0.f,0.f,0.f},{0.f,0.f,0.f,0.f},
                  {0.f,0.f,0.f,0.f},{0.f,0.f,0.f,0.f}};
#pragma unroll
  for (int kb = 0; kb < 16; ++kb) {
    const float4 g0 = *reinterpret_cast<const float4*>(gp + (kb << 5));
    const float4 g1 = *reinterpret_cast<const float4*>(gp + (kb << 5) + 4);
    const float4 b0 = *reinterpret_cast<const float4*>(bp + (kb << 5));
    const float4 b1 = *reinterpret_cast<const float4*>(bp + (kb << 5) + 4);
    S8U u; u.v = ar[kb];
    const float r0 = __uint_as_float(u.u[0] << 16);
    const float r1 = __uint_as_float(u.u[0] & 0xFFFF0000u);
    const float r2 = __uint_as_float(u.u[1] << 16);
    const float r3 = __uint_as_float(u.u[1] & 0xFFFF0000u);
    const float r4 = __uint_as_float(u.u[2] << 16);
    const float r5 = __uint_as_float(u.u[2] & 0xFFFF0000u);
    const float r6 = __uint_as_float(u.u[3] << 16);
    const float r7 = __uint_as_float(u.u[3] & 0xFFFF0000u);
    const float n0 = fmaf(r0, rs, nmr), n1 = fmaf(r1, rs, nmr);
    const float n2 = fmaf(r2, rs, nmr), n3 = fmaf(r3, rs, nmr);
    const float n4 = fmaf(r4, rs, nmr), n5 = fmaf(r5, rs, nmr);
    const float n6 = fmaf(r6, rs, nmr), n7 = fmaf(r7, rs, nmr);
    const short8 af = pack8(
        fmaxf(fmaf(n0, g0.x, b0.x), 0.f), fmaxf(fmaf(n1, g0.y, b0.y), 0.f),
        fmaxf(fmaf(n2, g0.z, b0.z), 0.f), fmaxf(fmaf(n3, g0.w, b0.w), 0.f),
        fmaxf(fmaf(n4, g1.x, b1.x), 0.f), fmaxf(fmaf(n5, g1.y, b1.y), 0.f),
        fmaxf(fmaf(n6, g1.z, b1.z), 0.f), fmaxf(fmaf(n7, g1.w, b1.w), 0.f));
#pragma unroll
    for (int nt = 0; nt < 4; ++nt) {
      const short8 bf = *reinterpret_cast<const short8*>(
          wfp + (size_t)nt * 32768 + (kb << 9));
      acc[nt] = __builtin_amdgcn_mfma_f32_16x16x32_bf16(af, bf, acc[nt], 0, 0, 0);
    }
  }

  // Aux GEMM from retained bf16 registers (unpack, normalize, repack).
  const float* agp = ln_ag + (w << 6) + (q << 3);
  const float* abp = ln_ab + (w << 6) + (q << 3);
  const unsigned short* afp = wfrag + 131072;
  f32x4 acca = {0.f,0.f,0.f,0.f};
#pragma unroll
  for (int kb = 0; kb < 2; ++kb) {
    const float4 g0 = *reinterpret_cast<const float4*>(agp + (kb << 5));
    const float4 g1 = *reinterpret_cast<const float4*>(agp + (kb << 5) + 4);
    const float4 b0 = *reinterpret_cast<const float4*>(abp + (kb << 5));
    const float4 b1 = *reinterpret_cast<const float4*>(abp + (kb << 5) + 4);
    S8U u; u.v = aar[kb];
    const float r0 = __uint_as_float(u.u[0] << 16);
    const float r1 = __uint_as_float(u.u[0] & 0xFFFF0000u);
    const float r2 = __uint_as_float(u.u[1] << 16);
    const float r3 = __uint_as_float(u.u[1] & 0xFFFF0000u);
    const float r4 = __uint_as_float(u.u[2] << 16);
    const float r5 = __uint_as_float(u.u[2] & 0xFFFF0000u);
    const float r6 = __uint_as_float(u.u[3] << 16);
    const float r7 = __uint_as_float(u.u[3] & 0xFFFF0000u);
    const short8 af = pack8(
        fmaxf(fmaf(fmaf(r0, ars, anmr), g0.x, b0.x), 0.f),
        fmaxf(fmaf(fmaf(r1, ars, anmr), g0.y, b0.y), 0.f),
        fmaxf(fmaf(fmaf(r2, ars, anmr), g0.z, b0.z), 0.f),
        fmaxf(fmaf(fmaf(r3, ars, anmr), g0.w, b0.w), 0.f),
        fmaxf(fmaf(fmaf(r4, ars, anmr), g1.x, b1.x), 0.f),
        fmaxf(fmaf(fmaf(r5, ars, anmr), g1.y, b1.y), 0.f),
        fmaxf(fmaf(fmaf(r6, ars, anmr), g1.z, b1.z), 0.f),
        fmaxf(fmaf(fmaf(r7, ars, anmr), g1.w, b1.w), 0.f));
    const short8 bf = *reinterpret_cast<const short8*>(
        afp + ((size_t)(((w << 1) + kb) * 64 + lane) << 3));
    acca = __builtin_amdgcn_mfma_f32_16x16x32_bf16(af, bf, acca, 0, 0, 0);
  }

  // Partial D tiles to LDS: D[row = q*4+reg][f = nt*16 + m] for this k-quarter.
#pragma unroll
  for (int nt = 0; nt < 4; ++nt)
#pragma unroll
    for (int r = 0; r < 4; ++r)
      part[w][(q << 2) + r][(nt << 4) + m] = acc[nt][r];
  if (m < 8) {
#pragma unroll
    for (int r = 0; r < 4; ++r)
      auxpart[w][(q << 2) + r][m] = acca[r];
  }
  __syncthreads();

  // ------------- epilogue: reduce partials, gates, scale pair --------------
  // Lane handles row rl = w*4 + q, main f-quad f0 = 4m; aux f = m&7.
  const int rl = (w << 2) + q;
  const int f0 = m << 2;
  const float4 p0 = *reinterpret_cast<const float4*>(&part[0][rl][f0]);
  const float4 p1 = *reinterpret_cast<const float4*>(&part[1][rl][f0]);
  const float4 p2 = *reinterpret_cast<const float4*>(&part[2][rl][f0]);
  const float4 p3 = *reinterpret_cast<const float4*>(&part[3][rl][f0]);
  const float4 blv = reinterpret_cast<const float4*>(b_lin)[m];
  float sgs = sigmoidf_(p0.x + p1.x + p2.x + p3.x + blv.x)
            + sigmoidf_(p0.y + p1.y + p2.y + p3.y + blv.y)
            + sigmoidf_(p0.z + p1.z + p2.z + p3.z + blv.z)
            + sigmoidf_(p0.w + p1.w + p2.w + p3.w + blv.w);
  sgs += __shfl_xor(sgs, 1);
  sgs += __shfl_xor(sgs, 2);
  sgs += __shfl_xor(sgs, 4);
  sgs += __shfl_xor(sgs, 8);            // sum over all 64 f
  const float gate = sgs * (1.f / 64.f);

  const int fa = m & 7;
  float av4 = auxpart[0][rl][fa] + auxpart[1][rl][fa] +
              auxpart[2][rl][fa] + auxpart[3][rl][fa];
  float axs = sigmoidf_(av4 + b_aux[fa]);
  axs = (m < 8) ? axs : 0.f;
  axs += __shfl_xor(axs, 1);
  axs += __shfl_xor(axs, 2);
  axs += __shfl_xor(axs, 4);
  axs += __shfl_xor(axs, 8);            // sum of 8 aux sigmoids (all m-lanes)
  const float auxg = axs * 0.125f;

  const float logit = gw[0] * rsigf(gate) + agw[0] * rsigf(auxg);
  const float g = sigmoidf_(logit) * auxw[base + rl];
  if (m == 0) out_g[base + rl] = g;

#pragma unroll
  for (int i = 0; i < 4; ++i) {
    const float gi = __shfl(g, (i << 4));   // lane 16i holds row w*4+i's g
    const int row = base + (w << 2) + i;
    const float4* pp = reinterpret_cast<const float4*>(pair + (size_t)row * 1024);
    float4* oo = reinterpret_cast<float4*>(out + (size_t)row * 1024);
#pragma unroll
    for (int j = 0; j < 4; ++j) {
      float4 pv = pp[lane + (j << 6)];
      pv.x *= gi; pv.y *= gi; pv.z *= gi; pv.w *= gi;
      oo[lane + (j << 6)] = pv;
    }
  }
}

extern "C" void kernel_launch(void* const* d_in, const int* in_sizes, int n_in,
                              void* d_out, int out_size, void* d_ws, size_t ws_size,
                              hipStream_t stream) {
  const float* unary = (const float*)d_in[0];
  const float* pair  = (const float*)d_in[1];
  const float* aux   = (const float*)d_in[2];
  const float* auxw  = (const float*)d_in[3];
  const float* ln_g  = (const float*)d_in[4];
  const float* ln_b  = (const float*)d_in[5];
  const float* W     = (const float*)d_in[6];
  const float* b     = (const float*)d_in[7];
  const float* ln_ag = (const float*)d_in[8];
  const float* ln_ab = (const float*)d_in[9];
  const float* W_aux = (const float*)d_in[10];
  const float* b_aux = (const float*)d_in[11];
  const float* gw    = (const float*)d_in[12];
  const float* agw   = (const float*)d_in[13];

  const int N = in_sizes[3];            // 32768
  unsigned short* wfrag = (unsigned short*)d_ws;   // 256 KB main + 8 KB aux frags
  float* out = (float*)d_out;
  float* out_g = out + (size_t)N * 1024;

  prep_frags<<<264, 64, 0, stream>>>(W, W_aux, wfrag);
  fused_main<<<N / 16, 256, 0, stream>>>(unary, pair, aux, auxw, ln_g, ln_b, b,
                                         ln_ag, ln_ab, b_aux, gw, agw,
                                         wfrag, out, out_g);
}